// Round 2
// baseline (289.339 us; speedup 1.0000x reference)
//
#include <hip/hip_runtime.h>
#include <stdint.h>

typedef __attribute__((ext_vector_type(8))) short short8;
typedef __attribute__((ext_vector_type(4))) float f32x4;

// ---- problem constants ----
#define TOKENS 4096
#define DDIM 1024
#define IDIM 512
#define NEXP 16
#define NEXP1 17
#define CSTRIDE 32    // counts padded: one counter per 128 B (atomic line ping-pong fix)
#define MAXMB 112     // max total m-blocks: 32 (shared) + sum ceil(cnt/128) <= 111

// ---- workspace layout (bytes) ----
#define OFF_WGU   0ull           // 17*1024*1024*2   [e][n'(interleaved 2i+{g,u})][k] bf16
#define OFF_WD    35651584ull    // 17*1024*512*2    [e][n(D)][k(I)] bf16
#define OFF_XB    53477376ull    // 4096*1024*2      x in bf16
#define OFF_HGU   61865984ull    // 12288*1024*2     gemmB out (expert outputs per slot)
#define OFF_H     87031808ull    // 12288*512*2      silu(g)*u   (gemmA out, fused)
#define OFF_TOK   99614720ull    // 17*4096*4
#define OFF_REC   99893248ull    // 4096*8  per-token (e,p) records
#define OFF_WREC  99926016ull    // 4096*8  per-token (w0,w1)
#define OFF_CNT   100171776ull   // 17*128 padded counters (4096 B reserved)
#define OFF_BASE  100175872ull   // bases[18] then mbp[18] at +80B

__device__ __forceinline__ float bf2f(unsigned short u) {
    union { uint32_t i; float f; } v; v.i = ((uint32_t)u) << 16; return v.f;
}
__device__ __forceinline__ unsigned short f2bf(float f) {
    union { float f; uint32_t i; } v; v.f = f;
    uint32_t r = v.i + 0x7FFFu + ((v.i >> 16) & 1u);  // RNE
    return (unsigned short)(r >> 16);
}
// async 16B global->LDS (dest = wave-uniform base + lane*16). imm offset ALWAYS 0 —
// non-zero imm offset on this instruction produced NaN (round 10): unverified HW path.
__device__ __forceinline__ void cp16(const unsigned short* g, unsigned short* l) {
    __builtin_amdgcn_global_load_lds(
        (const __attribute__((address_space(1))) uint32_t*)g,
        (__attribute__((address_space(3))) uint32_t*)l, 16, 0, 0);
}

// ---- weight transpose + fp32->bf16. Wgu interleaved: col n' = 2*i + m.
//      Store pass: 8-lane groups write full 128-B lines (fully coalesced). ----
__global__ __launch_bounds__(256)
void k_transpose(const float* __restrict__ eg, const float* __restrict__ eu,
                 const float* __restrict__ ed, const float* __restrict__ sg,
                 const float* __restrict__ su, const float* __restrict__ sd,
                 unsigned short* __restrict__ Wgu, unsigned short* __restrict__ Wd)
{
    int z = blockIdx.z;
    int e = z / 3, m = z % 3;
    int R = (m == 2) ? 512 : 1024;   // src rows (k)
    int C = (m == 2) ? 1024 : 512;   // src cols (n)
    int r0 = blockIdx.y * 64, c0 = blockIdx.x * 64;
    if (r0 >= R || c0 >= C) return;
    const float* src;
    if (m == 0)      src = (e < 16) ? eg + (size_t)e * 524288 : sg;
    else if (m == 1) src = (e < 16) ? eu + (size_t)e * 524288 : su;
    else             src = (e < 16) ? ed + (size_t)e * 524288 : sd;

    __shared__ float tl[64 * 65];
    const int tid = threadIdx.x;

    {
        const int lr = tid >> 4;          // 0..15
        const int lc = (tid & 15) * 4;    // 0..60
        #pragma unroll
        for (int ps = 0; ps < 4; ++ps) {
            int r = ps * 16 + lr;
            float4 v = *(const float4*)(src + (size_t)(r0 + r) * C + (c0 + lc));
            float* d = &tl[r * 65 + lc];
            d[0] = v.x; d[1] = v.y; d[2] = v.z; d[3] = v.w;
        }
    }
    __syncthreads();

    {
        const int w = tid >> 6, l = tid & 63;
        const int kb = (l & 7) * 8;       // k-chunk within tile (8 elems = 16 B)
        #pragma unroll
        for (int p = 0; p < 2; ++p) {
            int nl = p * 32 + w * 8 + (l >> 3);
            unsigned short ov[8];
            #pragma unroll
            for (int j = 0; j < 8; ++j)
                ov[j] = f2bf(tl[(kb + j) * 65 + nl]);
            int n = c0 + nl;
            int k = r0 + kb;
            unsigned short* dst;
            if (m < 2) dst = Wgu + (size_t)e * 1048576 + (size_t)(2 * n + m) * 1024 + k;
            else       dst = Wd  + (size_t)e * 524288  + (size_t)n * 512 + k;
            *(uint4*)dst = *(uint4*)ov;
        }
    }
}

// ---- x -> bf16, fill shared-expert token list ----
__global__ void k_xconv(const float* __restrict__ x, unsigned short* __restrict__ xb,
                        int* __restrict__ tok)
{
    int i = blockIdx.x * 256 + threadIdx.x;   // 1048576 float4 groups, exact
    float4 v = ((const float4*)x)[i];
    ushort4 b;
    b.x = f2bf(v.x); b.y = f2bf(v.y); b.z = f2bf(v.z); b.w = f2bf(v.w);
    ((ushort4*)xb)[i] = b;
    if (i < TOKENS) tok[16 * 4096 + i] = i;
}

// ---- router: expert-phased LDS staging, fp64 accumulate, padded atomics ----
__global__ __launch_bounds__(512, 4)
void k_router(const float* __restrict__ x, const float* __restrict__ gw,
              const float* __restrict__ gb, int* __restrict__ tok,
              int2* __restrict__ rec, float2* __restrict__ wrec,
              int* __restrict__ counts)
{
    __shared__ float gws[1024 * 12];             // 49152 B

    const int t = blockIdx.x * 8 + (threadIdx.x >> 6);   // 512 blocks * 8 waves
    const int lane = threadIdx.x & 63;
    const float* xr = x + (size_t)t * DDIM;

    float xv[16];
    #pragma unroll
    for (int kk = 0; kk < 16; ++kk) xv[kk] = xr[kk * 64 + lane];

    float v[16];

    for (int p = 0; p < 2; ++p) {
        __syncthreads();
        #pragma unroll
        for (int c = 0; c < 4; ++c) {
            int idx = threadIdx.x + c * 512;     // 0..2047
            int k = idx >> 1;
            int h = (idx & 1) * 4;               // 0 or 4 floats
            float4 g4 = *(const float4*)(gw + k * 16 + p * 8 + h);
            *(float4*)&gws[k * 12 + h] = g4;
        }
        __syncthreads();

        double a[8];
        #pragma unroll
        for (int j = 0; j < 8; ++j) a[j] = 0.0;

        #pragma unroll
        for (int kk = 0; kk < 16; ++kk) {
            int kl = kk * 64 + lane;
            float4 gA = *(const float4*)&gws[kl * 12];
            float4 gB = *(const float4*)&gws[kl * 12 + 4];
            double xd = (double)xv[kk];
            a[0] += xd * (double)gA.x; a[1] += xd * (double)gA.y;
            a[2] += xd * (double)gA.z; a[3] += xd * (double)gA.w;
            a[4] += xd * (double)gB.x; a[5] += xd * (double)gB.y;
            a[6] += xd * (double)gB.z; a[7] += xd * (double)gB.w;
        }

        #pragma unroll
        for (int off = 32; off > 0; off >>= 1) {
            #pragma unroll
            for (int j = 0; j < 8; ++j)
                a[j] += __shfl_xor(a[j], off, 64);
        }

        #pragma unroll
        for (int j = 0; j < 8; ++j)
            v[p * 8 + j] = 1.0f / (1.0f + expf(-(float)(a[j] + (double)gb[p * 8 + j])));
    }

    if (lane == 0) {
        int i0 = 0;
        #pragma unroll
        for (int e = 1; e < 16; ++e) if (v[e] > v[i0]) i0 = e;
        int i1 = (i0 == 0) ? 1 : 0;
        #pragma unroll
        for (int e = 0; e < 16; ++e) if (e != i0 && e != i1 && v[e] > v[i1]) i1 = e;
        float s = v[i0] + v[i1];
        float w0 = v[i0] / s, w1 = v[i1] / s;
        int p0 = atomicAdd(&counts[i0 * CSTRIDE], 1);   // padded: 1 line per expert
        tok[i0 * 4096 + p0] = t;
        int p1 = atomicAdd(&counts[i1 * CSTRIDE], 1);
        tok[i1 * 4096 + p1] = t;
        rec[t]  = make_int2(i0 * 4096 + p0, i1 * 4096 + p1);
        wrec[t] = make_float2(w0, w1);
    }
}

// ---- prefix: slot bases + compacted m-block table ----
__global__ void k_prefix(int* counts, int* bases, int* mbp)
{
    if (threadIdx.x == 0 && blockIdx.x == 0) {
        counts[16 * CSTRIDE] = TOKENS;
        int a = 0, b = 0;
        for (int e = 0; e < NEXP1; ++e) {
            int c = counts[e * CSTRIDE];
            bases[e] = a; a += c;
            mbp[e] = b;  b += (c + 127) >> 7;
        }
        bases[17] = a;
        mbp[17] = b;
    }
}

// ---- grouped GEMM, 128x128 tile, BK=64, PREFETCH-DOUBLE-BUFFERED (T3-minimum):
//      stage tile t+1 into buf^1 BEFORE ds_read+MFMA of tile t; single
//      vmcnt(0)+barrier per k-step (compiler emits it at __syncthreads).
//      LDS layout: [buf][khalf][128 rows][32 elems], rows = 64 B.
//      Bank-conflict fix (rule #21: both-sides): global SOURCE segment permuted
//      lseg ^= (lrow>>1)&3 (LDS dest stays linear for global_load_lds), read
//      side uses q ^= (mc>>1)&3  -> 2 lanes/bank (free) instead of 8-way. ----
// MODE 0: A = xb gathered, K=1024, B = Wgu interleaved -> fused silu -> H (bf16)
// MODE 1: A = H (contiguous slots), K=512, B = Wd -> Hgu (bf16)

#define STAGE8(BUF, KK) do {                                                  \
    cp16(ag0 + (KK),      &As[BUF][0][wb]);                                   \
    cp16(ag0 + (KK) + 32, &As[BUF][1][wb]);                                   \
    cp16(ag1 + (KK),      &As[BUF][0][wb + 512]);                             \
    cp16(ag1 + (KK) + 32, &As[BUF][1][wb + 512]);                             \
    cp16(bg0 + (KK),      &Bs[BUF][0][wb]);                                   \
    cp16(bg0 + (KK) + 32, &Bs[BUF][1][wb]);                                   \
    cp16(bg1 + (KK),      &Bs[BUF][0][wb + 512]);                             \
    cp16(bg1 + (KK) + 32, &Bs[BUF][1][wb + 512]);                             \
} while (0)

#define GSTEP(BUF, PRE, KNEXT) do {                                           \
    if (PRE) STAGE8((BUF) ^ 1, KNEXT);                                        \
    short8 va0[4], va1[4], vb0[4], vb1[4];                                    \
    _Pragma("unroll")                                                         \
    for (int i = 0; i < 4; ++i) {                                             \
        va0[i] = *(const short8*)&As[BUF][0][(wm*64 + i*16 + mc)*32 + qs];    \
        va1[i] = *(const short8*)&As[BUF][1][(wm*64 + i*16 + mc)*32 + qs];    \
    }                                                                         \
    _Pragma("unroll")                                                         \
    for (int j = 0; j < 4; ++j) {                                             \
        vb0[j] = *(const short8*)&Bs[BUF][0][(wn*64 + j*16 + mc)*32 + qs];    \
        vb1[j] = *(const short8*)&Bs[BUF][1][(wn*64 + j*16 + mc)*32 + qs];    \
    }                                                                         \
    _Pragma("unroll")                                                         \
    for (int i = 0; i < 4; ++i)                                               \
        _Pragma("unroll")                                                     \
        for (int j = 0; j < 4; ++j)                                           \
            acc[i][j] = __builtin_amdgcn_mfma_f32_16x16x32_bf16(va0[i], vb0[j], acc[i][j], 0, 0, 0); \
    _Pragma("unroll")                                                         \
    for (int i = 0; i < 4; ++i)                                               \
        _Pragma("unroll")                                                     \
        for (int j = 0; j < 4; ++j)                                           \
            acc[i][j] = __builtin_amdgcn_mfma_f32_16x16x32_bf16(va1[i], vb1[j], acc[i][j], 0, 0, 0); \
} while (0)

template <int MODE>
__global__ __launch_bounds__(256, 2)
void k_gemm(const unsigned short* __restrict__ Amat, const unsigned short* __restrict__ Bmat,
            const int* __restrict__ tok, const int* __restrict__ counts,
            const int* __restrict__ bases, const int* __restrict__ mbp,
            unsigned short* __restrict__ Out)
{
    constexpr int K = (MODE == 0) ? 1024 : 512;
    const int my = blockIdx.y;
    if (my >= mbp[17]) return;
    int e = 0;
    while (my >= mbp[e + 1]) ++e;          // <=17 scalar iterations
    const int cnt = counts[e * CSTRIDE];
    const int m0 = (my - mbp[e]) * 128;
    const int n0 = blockIdx.x * 128;
    const int base = bases[e];

    // [buf][khalf][128*32] bf16 = 64 KB total (2 blocks/CU)
    __shared__ unsigned short As[2][2][128 * 32];
    __shared__ unsigned short Bs[2][2][128 * 32];

    const int tid  = threadIdx.x;
    const int wave = tid >> 6;
    const int lane = tid & 63;
    const int lrow = lane >> 2;                         // 0..15 (row within 16-row chunk)
    const int lseg = (lane & 3) ^ ((lrow >> 1) & 3);    // SWIZZLED source 16B segment

    const int wb = wave * 1024;                         // wave chunk base in each khalf plane

    int ar0 = m0 + wave * 32 + lrow;      if (ar0 > cnt - 1) ar0 = cnt - 1;
    int ar1 = m0 + wave * 32 + 16 + lrow; if (ar1 > cnt - 1) ar1 = cnt - 1;
    size_t ai0, ai1;
    if (MODE == 0) { ai0 = (size_t)tok[e * 4096 + ar0]; ai1 = (size_t)tok[e * 4096 + ar1]; }
    else           { ai0 = (size_t)(base + ar0);        ai1 = (size_t)(base + ar1); }
    const unsigned short* ag0 = Amat + ai0 * K + lseg * 8;
    const unsigned short* ag1 = Amat + ai1 * K + lseg * 8;
    const size_t eoff = (size_t)e * 1024 * K;
    const unsigned short* bg0 = Bmat + eoff + (size_t)(n0 + wave * 32 + lrow) * K + lseg * 8;
    const unsigned short* bg1 = Bmat + eoff + (size_t)(n0 + wave * 32 + 16 + lrow) * K + lseg * 8;

    const int wm = wave & 1, wn = wave >> 1;
    const int q = lane >> 4, mc = lane & 15;
    const int qs = (q ^ ((mc >> 1) & 3)) * 8;           // SWIZZLED read seg (elems)

    f32x4 acc[4][4];
    #pragma unroll
    for (int i = 0; i < 4; ++i)
        #pragma unroll
        for (int j = 0; j < 4; ++j) acc[i][j] = (f32x4){0.f, 0.f, 0.f, 0.f};

    // prologue: stage first tile into buf0
    STAGE8(0, 0);
    __syncthreads();   // compiler-inserted vmcnt(0) drains the prologue loads

    for (int k0 = 0; k0 < K; k0 += 128) {
        // compute buf0 @ k0, prefetch buf1 @ k0+64 (always in range: k0 <= K-128)
        GSTEP(0, 1, k0 + 64);
        __syncthreads();
        // compute buf1 @ k0+64, prefetch buf0 @ k0+128 (unless last)
        GSTEP(1, (k0 + 128 < K), k0 + 128);
        __syncthreads();
    }

    // epilogue: C/D layout col=lane&15, row=(lane>>4)*4+reg  [m89-verified]
    #pragma unroll
    for (int i = 0; i < 4; ++i) {
        int lr = wm * 64 + i * 16 + q * 4;
        #pragma unroll
        for (int r = 0; r < 4; ++r) {
            int mrow = m0 + lr + r;
            if (mrow >= cnt) continue;
            #pragma unroll
            for (int j = 0; j < 4; ++j) {
                int gc = n0 + wn * 64 + j * 16 + mc;
                float val = acc[i][j][r];
                if (MODE == 0) {
                    // interleaved cols: even gc = gate(i=gc/2), odd = up. Pair via lane^1.
                    float other = __shfl_xor(val, 1, 64);
                    float g = (mc & 1) ? other : val;
                    float u = (mc & 1) ? val : other;
                    float h = g / (1.0f + __expf(-g)) * u;
                    if ((mc & 1) == 0)
                        Out[(size_t)(base + mrow) * 512 + (gc >> 1)] = f2bf(h);
                } else {
                    Out[(size_t)(base + mrow) * 1024 + gc] = f2bf(val);
                }
            }
        }
    }
}

// ---- out[t] = x[t] + Hs[shared] + w0*Hs[s0] + w1*Hs[s1] ----
__global__ void k_combine(const float* __restrict__ x, const unsigned short* __restrict__ Hs,
                          const int2* __restrict__ rec, const float2* __restrict__ wrec,
                          const int* __restrict__ bases, float* __restrict__ out)
{
    int t = blockIdx.x * 2 + (threadIdx.x >> 7);   // 2048 blocks * 2 tokens
    int c = (threadIdx.x & 127) * 8;
    int2 r = rec[t];
    float2 w = wrec[t];
    int s0 = bases[r.x >> 12] + (r.x & 4095);
    int s1 = bases[r.y >> 12] + (r.y & 4095);
    int ss = 8192 + t;                              // shared list base is always 8192

    unsigned short h0[8], h1[8], hs[8];
    *(uint4*)h0 = *(const uint4*)(Hs + (size_t)s0 * 1024 + c);
    *(uint4*)h1 = *(const uint4*)(Hs + (size_t)s1 * 1024 + c);
    *(uint4*)hs = *(const uint4*)(Hs + (size_t)ss * 1024 + c);
    const float* xr = x + (size_t)t * 1024 + c;
    float o[8];
    #pragma unroll
    for (int j = 0; j < 8; ++j)
        o[j] = xr[j] + bf2f(hs[j]) + w.x * bf2f(h0[j]) + w.y * bf2f(h1[j]);
    float* orow = out + (size_t)t * 1024 + c;
    *(float4*)orow       = *(float4*)&o[0];
    *(float4*)(orow + 4) = *(float4*)&o[4];
}

extern "C" void kernel_launch(void* const* d_in, const int* in_sizes, int n_in,
                              void* d_out, int out_size, void* d_ws, size_t ws_size,
                              hipStream_t stream)
{
    const float* x  = (const float*)d_in[0];
    const float* gw = (const float*)d_in[1];
    const float* gb = (const float*)d_in[2];
    const float* sg = (const float*)d_in[3];
    const float* su = (const float*)d_in[4];
    const float* sd = (const float*)d_in[5];
    const float* eg = (const float*)d_in[6];
    const float* eu = (const float*)d_in[7];
    const float* ed = (const float*)d_in[8];
    float* out = (float*)d_out;
    char* ws = (char*)d_ws;

    unsigned short* Wgu = (unsigned short*)(ws + OFF_WGU);
    unsigned short* Wd  = (unsigned short*)(ws + OFF_WD);
    unsigned short* xb  = (unsigned short*)(ws + OFF_XB);
    unsigned short* Hgu = (unsigned short*)(ws + OFF_HGU);
    unsigned short* H   = (unsigned short*)(ws + OFF_H);
    int*    tok   = (int*)(ws + OFF_TOK);
    int2*   rec   = (int2*)(ws + OFF_REC);
    float2* wrec  = (float2*)(ws + OFF_WREC);
    int*    counts= (int*)(ws + OFF_CNT);
    int*    bases = (int*)(ws + OFF_BASE);
    int*    mbp   = bases + 20;

    hipMemsetAsync(counts, 0, 4096, stream);
    k_transpose<<<dim3(16, 16, 51), 256, 0, stream>>>(eg, eu, ed, sg, su, sd, Wgu, Wd);
    k_xconv<<<4096, 256, 0, stream>>>(x, xb, tok);
    k_router<<<512, 512, 0, stream>>>(x, gw, gb, tok, rec, wrec, counts);
    k_prefix<<<1, 64, 0, stream>>>(counts, bases, mbp);
    k_gemm<0><<<dim3(8, MAXMB), 256, 0, stream>>>(xb, Wgu, tok, counts, bases, mbp, H);
    k_gemm<1><<<dim3(8, MAXMB), 256, 0, stream>>>(H, Wd, tok, counts, bases, mbp, Hgu);
    k_combine<<<2048, 256, 0, stream>>>(x, Hgu, rec, wrec, bases, out);
}

// Round 5
// 284.448 us; speedup vs baseline: 1.0172x; 1.0172x over previous
//
#include <hip/hip_runtime.h>
#include <stdint.h>

typedef __attribute__((ext_vector_type(8))) short short8;
typedef __attribute__((ext_vector_type(4))) float f32x4;

// ---- problem constants ----
#define TOKENS 4096
#define DDIM 1024
#define IDIM 512
#define NEXP 16
#define NEXP1 17
#define CSTRIDE 32    // counts padded: one counter per 128 B (atomic line ping-pong fix)
#define MAXMB 112     // max total m-blocks: 32 (shared) + sum ceil(cnt/128) <= 111

// ---- workspace layout (bytes) ----
#define OFF_WGU   0ull           // 17*1024*1024*2   [e][n'(interleaved 2i+{g,u})][k] bf16
#define OFF_WD    35651584ull    // 17*1024*512*2    [e][n(D)][k(I)] bf16
#define OFF_XB    53477376ull    // 4096*1024*2      x in bf16
#define OFF_HGU   61865984ull    // 12288*1024*2     gemmB out (expert outputs per slot)
#define OFF_H     87031808ull    // 12288*512*2      silu(g)*u   (gemmA out, fused)
#define OFF_TOK   99614720ull    // 17*4096*4
#define OFF_REC   99893248ull    // 4096*8  per-token (e,p) records
#define OFF_WREC  99926016ull    // 4096*8  per-token (w0,w1)
#define OFF_CNT   100171776ull   // 17*128 padded counters (4096 B reserved)
#define OFF_BASE  100175872ull   // bases[20] then mbp[20] at +80B (both 16B-aligned)

__device__ __forceinline__ float bf2f(unsigned short u) {
    union { uint32_t i; float f; } v; v.i = ((uint32_t)u) << 16; return v.f;
}
__device__ __forceinline__ unsigned short f2bf(float f) {
    union { float f; uint32_t i; } v; v.f = f;
    uint32_t r = v.i + 0x7FFFu + ((v.i >> 16) & 1u);  // RNE
    return (unsigned short)(r >> 16);
}
// async 16B global->LDS (dest = wave-uniform base + lane*16). imm offset ALWAYS 0 —
// non-zero imm offset on this instruction produced NaN (round 10): unverified HW path.
__device__ __forceinline__ void cp16(const unsigned short* g, unsigned short* l) {
    __builtin_amdgcn_global_load_lds(
        (const __attribute__((address_space(1))) uint32_t*)g,
        (__attribute__((address_space(3))) uint32_t*)l, 16, 0, 0);
}

// ---- weight transpose + fp32->bf16. Wgu interleaved: col n' = 2*i + m.
//      Store pass: 8-lane groups write full 128-B lines (fully coalesced). ----
__global__ __launch_bounds__(256)
void k_transpose(const float* __restrict__ eg, const float* __restrict__ eu,
                 const float* __restrict__ ed, const float* __restrict__ sg,
                 const float* __restrict__ su, const float* __restrict__ sd,
                 unsigned short* __restrict__ Wgu, unsigned short* __restrict__ Wd)
{
    int z = blockIdx.z;
    int e = z / 3, m = z % 3;
    int R = (m == 2) ? 512 : 1024;   // src rows (k)
    int C = (m == 2) ? 1024 : 512;   // src cols (n)
    int r0 = blockIdx.y * 64, c0 = blockIdx.x * 64;
    if (r0 >= R || c0 >= C) return;
    const float* src;
    if (m == 0)      src = (e < 16) ? eg + (size_t)e * 524288 : sg;
    else if (m == 1) src = (e < 16) ? eu + (size_t)e * 524288 : su;
    else             src = (e < 16) ? ed + (size_t)e * 524288 : sd;

    __shared__ float tl[64 * 65];
    const int tid = threadIdx.x;

    {
        const int lr = tid >> 4;          // 0..15
        const int lc = (tid & 15) * 4;    // 0..60
        #pragma unroll
        for (int ps = 0; ps < 4; ++ps) {
            int r = ps * 16 + lr;
            float4 v = *(const float4*)(src + (size_t)(r0 + r) * C + (c0 + lc));
            float* d = &tl[r * 65 + lc];
            d[0] = v.x; d[1] = v.y; d[2] = v.z; d[3] = v.w;
        }
    }
    __syncthreads();

    {
        const int w = tid >> 6, l = tid & 63;
        const int kb = (l & 7) * 8;       // k-chunk within tile (8 elems = 16 B)
        #pragma unroll
        for (int p = 0; p < 2; ++p) {
            int nl = p * 32 + w * 8 + (l >> 3);
            unsigned short ov[8];
            #pragma unroll
            for (int j = 0; j < 8; ++j)
                ov[j] = f2bf(tl[(kb + j) * 65 + nl]);
            int n = c0 + nl;
            int k = r0 + kb;
            unsigned short* dst;
            if (m < 2) dst = Wgu + (size_t)e * 1048576 + (size_t)(2 * n + m) * 1024 + k;
            else       dst = Wd  + (size_t)e * 524288  + (size_t)n * 512 + k;
            *(uint4*)dst = *(uint4*)ov;
        }
    }
}

// ---- x -> bf16, fill shared-expert token list ----
__global__ void k_xconv(const float* __restrict__ x, unsigned short* __restrict__ xb,
                        int* __restrict__ tok)
{
    int i = blockIdx.x * 256 + threadIdx.x;   // 1048576 float4 groups, exact
    float4 v = ((const float4*)x)[i];
    ushort4 b;
    b.x = f2bf(v.x); b.y = f2bf(v.y); b.z = f2bf(v.z); b.w = f2bf(v.w);
    ((ushort4*)xb)[i] = b;
    if (i < TOKENS) tok[16 * 4096 + i] = i;
}

// ---- router: expert-phased LDS staging, fp64 accumulate, padded atomics ----
__global__ __launch_bounds__(512, 4)
void k_router(const float* __restrict__ x, const float* __restrict__ gw,
              const float* __restrict__ gb, int* __restrict__ tok,
              int2* __restrict__ rec, float2* __restrict__ wrec,
              int* __restrict__ counts)
{
    __shared__ float gws[1024 * 12];             // 49152 B

    const int t = blockIdx.x * 8 + (threadIdx.x >> 6);   // 512 blocks * 8 waves
    const int lane = threadIdx.x & 63;
    const float* xr = x + (size_t)t * DDIM;

    float xv[16];
    #pragma unroll
    for (int kk = 0; kk < 16; ++kk) xv[kk] = xr[kk * 64 + lane];

    float v[16];

    for (int p = 0; p < 2; ++p) {
        __syncthreads();
        #pragma unroll
        for (int c = 0; c < 4; ++c) {
            int idx = threadIdx.x + c * 512;     // 0..2047
            int k = idx >> 1;
            int h = (idx & 1) * 4;               // 0 or 4 floats
            float4 g4 = *(const float4*)(gw + k * 16 + p * 8 + h);
            *(float4*)&gws[k * 12 + h] = g4;
        }
        __syncthreads();

        double a[8];
        #pragma unroll
        for (int j = 0; j < 8; ++j) a[j] = 0.0;

        #pragma unroll
        for (int kk = 0; kk < 16; ++kk) {
            int kl = kk * 64 + lane;
            float4 gA = *(const float4*)&gws[kl * 12];
            float4 gB = *(const float4*)&gws[kl * 12 + 4];
            double xd = (double)xv[kk];
            a[0] += xd * (double)gA.x; a[1] += xd * (double)gA.y;
            a[2] += xd * (double)gA.z; a[3] += xd * (double)gA.w;
            a[4] += xd * (double)gB.x; a[5] += xd * (double)gB.y;
            a[6] += xd * (double)gB.z; a[7] += xd * (double)gB.w;
        }

        #pragma unroll
        for (int off = 32; off > 0; off >>= 1) {
            #pragma unroll
            for (int j = 0; j < 8; ++j)
                a[j] += __shfl_xor(a[j], off, 64);
        }

        #pragma unroll
        for (int j = 0; j < 8; ++j)
            v[p * 8 + j] = 1.0f / (1.0f + expf(-(float)(a[j] + (double)gb[p * 8 + j])));
    }

    if (lane == 0) {
        int i0 = 0;
        #pragma unroll
        for (int e = 1; e < 16; ++e) if (v[e] > v[i0]) i0 = e;
        int i1 = (i0 == 0) ? 1 : 0;
        #pragma unroll
        for (int e = 0; e < 16; ++e) if (e != i0 && e != i1 && v[e] > v[i1]) i1 = e;
        float s = v[i0] + v[i1];
        float w0 = v[i0] / s, w1 = v[i1] / s;
        int p0 = atomicAdd(&counts[i0 * CSTRIDE], 1);   // padded: 1 line per expert
        tok[i0 * 4096 + p0] = t;
        int p1 = atomicAdd(&counts[i1 * CSTRIDE], 1);
        tok[i1 * 4096 + p1] = t;
        rec[t]  = make_int2(i0 * 4096 + p0, i1 * 4096 + p1);
        wrec[t] = make_float2(w0, w1);
    }
}

// ---- prefix: slot bases + compacted m-block table ----
__global__ void k_prefix(int* counts, int* bases, int* mbp)
{
    if (threadIdx.x == 0 && blockIdx.x == 0) {
        counts[16 * CSTRIDE] = TOKENS;
        int a = 0, b = 0;
        for (int e = 0; e < NEXP1; ++e) {
            int c = counts[e * CSTRIDE];
            bases[e] = a; a += c;
            mbp[e] = b;  b += (c + 127) >> 7;
        }
        bases[17] = a;
        mbp[17] = b;
        bases[18] = a; bases[19] = a;   // pad so int4 loads read defined data
        mbp[18] = b;   mbp[19] = b;
    }
}

// ---- grouped GEMM, 128x128 tile, BK=64, dbuf + COUNTED-VMCNT pipeline (T3+T4):
//      per phase: {stage buf^1 (8 cp16); s_waitcnt vmcnt(8) [buf ready, prefetch
//      stays in flight]; s_barrier; ds_read buf; MFMA; s_barrier [WAR: all waves
//      done reading buf before next phase overwrites]}. vmcnt never drained to 0
//      in the main loop (only in the final phase).
//      Bank-conflict fix (rule #21 both-sides): source segment permuted
//      lseg ^= (lrow>>1)&3 with linear LDS dest; read uses q ^= (mc>>1)&3. ----
// MODE 0: A = xb gathered, K=1024, B = Wgu interleaved -> fused silu -> H (bf16)
// MODE 1: A = H (contiguous slots), K=512, B = Wd -> Hgu (bf16)

#define WAITV8 asm volatile("s_waitcnt vmcnt(8)" ::: "memory")
#define WAITV0 asm volatile("s_waitcnt vmcnt(0)" ::: "memory")
#define BAR    __builtin_amdgcn_s_barrier()

#define STAGE8(BUF, KK) do {                                                  \
    cp16(ag0 + (KK),      &As[BUF][0][wb]);                                   \
    cp16(ag0 + (KK) + 32, &As[BUF][1][wb]);                                   \
    cp16(ag1 + (KK),      &As[BUF][0][wb + 512]);                             \
    cp16(ag1 + (KK) + 32, &As[BUF][1][wb + 512]);                             \
    cp16(bg0 + (KK),      &Bs[BUF][0][wb]);                                   \
    cp16(bg0 + (KK) + 32, &Bs[BUF][1][wb]);                                   \
    cp16(bg1 + (KK),      &Bs[BUF][0][wb + 512]);                             \
    cp16(bg1 + (KK) + 32, &Bs[BUF][1][wb + 512]);                             \
} while (0)

#define CSTEP(BUF) do {                                                       \
    short8 va0[4], va1[4], vb0[4], vb1[4];                                    \
    _Pragma("unroll")                                                         \
    for (int i = 0; i < 4; ++i) {                                             \
        va0[i] = *(const short8*)&As[BUF][0][(wm*64 + i*16 + mc)*32 + qs];    \
        va1[i] = *(const short8*)&As[BUF][1][(wm*64 + i*16 + mc)*32 + qs];    \
    }                                                                         \
    _Pragma("unroll")                                                         \
    for (int j = 0; j < 4; ++j) {                                             \
        vb0[j] = *(const short8*)&Bs[BUF][0][(wn*64 + j*16 + mc)*32 + qs];    \
        vb1[j] = *(const short8*)&Bs[BUF][1][(wn*64 + j*16 + mc)*32 + qs];    \
    }                                                                         \
    _Pragma("unroll")                                                         \
    for (int i = 0; i < 4; ++i)                                               \
        _Pragma("unroll")                                                     \
        for (int j = 0; j < 4; ++j)                                           \
            acc[i][j] = __builtin_amdgcn_mfma_f32_16x16x32_bf16(va0[i], vb0[j], acc[i][j], 0, 0, 0); \
    _Pragma("unroll")                                                         \
    for (int i = 0; i < 4; ++i)                                               \
        _Pragma("unroll")                                                     \
        for (int j = 0; j < 4; ++j)                                           \
            acc[i][j] = __builtin_amdgcn_mfma_f32_16x16x32_bf16(va1[i], vb1[j], acc[i][j], 0, 0, 0); \
} while (0)

template <int MODE>
__global__ __launch_bounds__(256, 2)
void k_gemm(const unsigned short* __restrict__ Amat, const unsigned short* __restrict__ Bmat,
            const int* __restrict__ tok, const int* __restrict__ counts,
            const int* __restrict__ bases, const int* __restrict__ mbp,
            unsigned short* __restrict__ Out)
{
    constexpr int K = (MODE == 0) ? 1024 : 512;
    const int my = blockIdx.y;

    // ---- parallel group lookup: 10 independent int4 loads, then cndmask select
    //      (replaces the serial 17-iteration dependent-load while loop) ----
    int bb[20], mm[20];
    {
        const int4* b4 = (const int4*)bases;
        const int4* m4 = (const int4*)mbp;
        #pragma unroll
        for (int i = 0; i < 5; ++i) {
            *(int4*)&bb[i * 4] = b4[i];
            *(int4*)&mm[i * 4] = m4[i];
        }
    }
    if (my >= mm[17]) return;
    int e = 0, me = mm[0], ba = bb[0], bn = bb[1];
    #pragma unroll
    for (int i = 1; i <= 16; ++i)
        if (my >= mm[i]) { e = i; me = mm[i]; ba = bb[i]; bn = bb[i + 1]; }
    const int cnt  = bn - ba;          // == counts[e] (prefix property)
    const int m0   = (my - me) * 128;
    const int base = ba;
    const int n0   = blockIdx.x * 128;

    // [buf][khalf][128*32] bf16 = 64 KB total (2 blocks/CU)
    __shared__ unsigned short As[2][2][128 * 32];
    __shared__ unsigned short Bs[2][2][128 * 32];

    const int tid  = threadIdx.x;
    const int wave = tid >> 6;
    const int lane = tid & 63;
    const int lrow = lane >> 2;                         // 0..15 (row within 16-row chunk)
    const int lseg = (lane & 3) ^ ((lrow >> 1) & 3);    // SWIZZLED source 16B segment

    const int wb = wave * 1024;                         // wave chunk base in each khalf plane

    int ar0 = m0 + wave * 32 + lrow;      if (ar0 > cnt - 1) ar0 = cnt - 1;
    int ar1 = m0 + wave * 32 + 16 + lrow; if (ar1 > cnt - 1) ar1 = cnt - 1;
    size_t ai0, ai1;
    if (MODE == 0) { ai0 = (size_t)tok[e * 4096 + ar0]; ai1 = (size_t)tok[e * 4096 + ar1]; }
    else           { ai0 = (size_t)(base + ar0);        ai1 = (size_t)(base + ar1); }
    const unsigned short* ag0 = Amat + ai0 * K + lseg * 8;
    const unsigned short* ag1 = Amat + ai1 * K + lseg * 8;
    const size_t eoff = (size_t)e * 1024 * K;
    const unsigned short* bg0 = Bmat + eoff + (size_t)(n0 + wave * 32 + lrow) * K + lseg * 8;
    const unsigned short* bg1 = Bmat + eoff + (size_t)(n0 + wave * 32 + 16 + lrow) * K + lseg * 8;

    const int wm = wave & 1, wn = wave >> 1;
    const int q = lane >> 4, mc = lane & 15;
    const int qs = (q ^ ((mc >> 1) & 3)) * 8;           // SWIZZLED read seg (elems)

    f32x4 acc[4][4];
    #pragma unroll
    for (int i = 0; i < 4; ++i)
        #pragma unroll
        for (int j = 0; j < 4; ++j) acc[i][j] = (f32x4){0.f, 0.f, 0.f, 0.f};

    // prologue: stage first tile into buf0 (8 loads in flight; no drain here)
    STAGE8(0, 0);

    for (int k0 = 0; k0 < K; k0 += 128) {
        // phase A: compute buf0 @ k0, prefetch buf1 @ k0+64 (in range: k0 <= K-128)
        STAGE8(1, k0 + 64);
        WAITV8;                 // buf0 loads done; buf1's 8 stay in flight
        BAR;                    // all waves' buf0 loads done
        CSTEP(0);
        BAR;                    // WAR: all waves finished reading buf0
        // phase B: compute buf1 @ k0+64, prefetch buf0 @ k0+128 (unless last)
        if (k0 + 128 < K) { STAGE8(0, k0 + 128); WAITV8; }
        else              { WAITV0; }
        BAR;
        CSTEP(1);
        BAR;
    }

    // epilogue: C/D layout col=lane&15, row=(lane>>4)*4+reg  [m89-verified]
    #pragma unroll
    for (int i = 0; i < 4; ++i) {
        int lr = wm * 64 + i * 16 + q * 4;
        #pragma unroll
        for (int r = 0; r < 4; ++r) {
            int mrow = m0 + lr + r;
            if (mrow >= cnt) continue;
            #pragma unroll
            for (int j = 0; j < 4; ++j) {
                int gc = n0 + wn * 64 + j * 16 + mc;
                float val = acc[i][j][r];
                if (MODE == 0) {
                    // interleaved cols: even gc = gate(i=gc/2), odd = up. Pair via lane^1.
                    float other = __shfl_xor(val, 1, 64);
                    float g = (mc & 1) ? other : val;
                    float u = (mc & 1) ? val : other;
                    float h = g / (1.0f + __expf(-g)) * u;
                    if ((mc & 1) == 0)
                        Out[(size_t)(base + mrow) * 512 + (gc >> 1)] = f2bf(h);
                } else {
                    Out[(size_t)(base + mrow) * 1024 + gc] = f2bf(val);
                }
            }
        }
    }
}

// ---- out[t] = x[t] + Hs[shared] + w0*Hs[s0] + w1*Hs[s1] ----
__global__ void k_combine(const float* __restrict__ x, const unsigned short* __restrict__ Hs,
                          const int2* __restrict__ rec, const float2* __restrict__ wrec,
                          const int* __restrict__ bases, float* __restrict__ out)
{
    int t = blockIdx.x * 2 + (threadIdx.x >> 7);   // 2048 blocks * 2 tokens
    int c = (threadIdx.x & 127) * 8;
    int2 r = rec[t];
    float2 w = wrec[t];
    int s0 = bases[r.x >> 12] + (r.x & 4095);
    int s1 = bases[r.y >> 12] + (r.y & 4095);
    int ss = 8192 + t;                              // shared list base is always 8192

    unsigned short h0[8], h1[8], hs[8];
    *(uint4*)h0 = *(const uint4*)(Hs + (size_t)s0 * 1024 + c);
    *(uint4*)h1 = *(const uint4*)(Hs + (size_t)s1 * 1024 + c);
    *(uint4*)hs = *(const uint4*)(Hs + (size_t)ss * 1024 + c);
    const float* xr = x + (size_t)t * 1024 + c;
    float o[8];
    #pragma unroll
    for (int j = 0; j < 8; ++j)
        o[j] = xr[j] + bf2f(hs[j]) + w.x * bf2f(h0[j]) + w.y * bf2f(h1[j]);
    float* orow = out + (size_t)t * 1024 + c;
    *(float4*)orow       = *(float4*)&o[0];
    *(float4*)(orow + 4) = *(float4*)&o[4];
}

extern "C" void kernel_launch(void* const* d_in, const int* in_sizes, int n_in,
                              void* d_out, int out_size, void* d_ws, size_t ws_size,
                              hipStream_t stream)
{
    const float* x  = (const float*)d_in[0];
    const float* gw = (const float*)d_in[1];
    const float* gb = (const float*)d_in[2];
    const float* sg = (const float*)d_in[3];
    const float* su = (const float*)d_in[4];
    const float* sd = (const float*)d_in[5];
    const float* eg = (const float*)d_in[6];
    const float* eu = (const float*)d_in[7];
    const float* ed = (const float*)d_in[8];
    float* out = (float*)d_out;
    char* ws = (char*)d_ws;

    unsigned short* Wgu = (unsigned short*)(ws + OFF_WGU);
    unsigned short* Wd  = (unsigned short*)(ws + OFF_WD);
    unsigned short* xb  = (unsigned short*)(ws + OFF_XB);
    unsigned short* Hgu = (unsigned short*)(ws + OFF_HGU);
    unsigned short* H   = (unsigned short*)(ws + OFF_H);
    int*    tok   = (int*)(ws + OFF_TOK);
    int2*   rec   = (int2*)(ws + OFF_REC);
    float2* wrec  = (float2*)(ws + OFF_WREC);
    int*    counts= (int*)(ws + OFF_CNT);
    int*    bases = (int*)(ws + OFF_BASE);
    int*    mbp   = bases + 20;

    (void)hipMemsetAsync(counts, 0, 4096, stream);
    k_transpose<<<dim3(16, 16, 51), 256, 0, stream>>>(eg, eu, ed, sg, su, sd, Wgu, Wd);
    k_xconv<<<4096, 256, 0, stream>>>(x, xb, tok);
    k_router<<<512, 512, 0, stream>>>(x, gw, gb, tok, rec, wrec, counts);
    k_prefix<<<1, 64, 0, stream>>>(counts, bases, mbp);
    k_gemm<0><<<dim3(8, MAXMB), 256, 0, stream>>>(xb, Wgu, tok, counts, bases, mbp, H);
    k_gemm<1><<<dim3(8, MAXMB), 256, 0, stream>>>(H, Wd, tok, counts, bases, mbp, Hgu);
    k_combine<<<2048, 256, 0, stream>>>(x, Hgu, rec, wrec, bases, out);
}